// Round 7
// baseline (125.013 us; speedup 1.0000x reference)
//
#include <hip/hip_runtime.h>

// DynamicEdgeWeightLearner — v7: persistent waves + 3-stage software pipeline.
//   h1 = relu(W1a@x[row] + W1b@x[col] + b1),  W1 = [W1a | W1b]
// Precompute per node (MFMA): ya = x@W1a^T + b1, yb = x@W1b^T, int8 (scale
// 127/2, clamp +-2). Tables 3.2 MB -> per-XCD L2-resident.
// Main kernel (EXACT, E%64==0): persistent grid-stride waves, each owns ~4
// 64-edge tiles. Steady state per tile: {issue gathers for t+1 (indices
// arrived last iter); issue index loads for t+2; compute t}. Double-buffered
// NAMED register sets (A/B) — no runtime-indexed arrays (scratch hazard).
// v6 lesson: nontemporal hints on index/out streams REGRESSED 5 us — reverted.
// Compute per tile: h1 = relu((qa+qb)*s) -> bf16 B-frag, swapped MFMA
// (C[ch][edge]), 2 shfl_xor reduce, coalesced 16-float store.

typedef __attribute__((ext_vector_type(8))) short short8v;  // 8 x bf16
typedef __attribute__((ext_vector_type(8))) char  char8v;   // 8 x int8
typedef __attribute__((ext_vector_type(4))) float f32x4;    // MFMA C/D frag

#define QSCALE   63.5f           // 127 / 2.0
#define QDEQ     0.015748031f    // 1 / 63.5

__device__ __forceinline__ unsigned short f32_bf16(float f) {
    union { float f; unsigned u; } v; v.f = f;
    return (unsigned short)((v.u + 0x7fffu + ((v.u >> 16) & 1u)) >> 16);  // RTNE
}
__device__ __forceinline__ short8v conv8(const float* src) {
    f32x4 f0 = *(const f32x4*)src;
    f32x4 f1 = *(const f32x4*)(src + 4);
    short8v r;
#pragma unroll
    for (int j = 0; j < 4; ++j) {
        r[j]     = (short)f32_bf16(f0[j]);
        r[4 + j] = (short)f32_bf16(f1[j]);
    }
    return r;
}
__device__ __forceinline__ char q8(float y) {
    int q = __float2int_rn(y * QSCALE);
    q = q > 127 ? 127 : (q < -127 ? -127 : q);
    return (char)q;
}

// ---------------- precompute: int8 ya = x@W1a^T + b1, yb = x@W1b^T ----------
__global__ __launch_bounds__(256) void precompute_y(
    const float* __restrict__ x, const float* __restrict__ W1,
    const float* __restrict__ b1,
    char* __restrict__ ya, char* __restrict__ yb, int N)
{
    const int t = threadIdx.x;
    const int w = t >> 6, l = t & 63, n = l & 15, g = l >> 4;
    const long long base = ((long long)blockIdx.x * 4 + w) * 16;
    if (base >= N) return;

    short8v Bf[2][2][2];
#pragma unroll
    for (int s = 0; s < 2; ++s)
#pragma unroll
        for (int nt = 0; nt < 2; ++nt)
#pragma unroll
            for (int q = 0; q < 2; ++q)
                Bf[s][nt][q] = conv8(W1 + (nt * 16 + n) * 128 + s * 64 + q * 32 + g * 8);

    long long row = base + n; if (row > (long long)N - 1) row = N - 1;
    const float* xr = x + row * 64;
    short8v a0 = conv8(xr + g * 8);
    short8v a1 = conv8(xr + 32 + g * 8);

    const float bA0 = b1[n], bA1 = b1[16 + n];
    f32x4 accA0 = {bA0, bA0, bA0, bA0};
    f32x4 accA1 = {bA1, bA1, bA1, bA1};
    f32x4 accB0 = {0.f, 0.f, 0.f, 0.f};
    f32x4 accB1 = {0.f, 0.f, 0.f, 0.f};

    accA0 = __builtin_amdgcn_mfma_f32_16x16x32_bf16(a0, Bf[0][0][0], accA0, 0, 0, 0);
    accA0 = __builtin_amdgcn_mfma_f32_16x16x32_bf16(a1, Bf[0][0][1], accA0, 0, 0, 0);
    accA1 = __builtin_amdgcn_mfma_f32_16x16x32_bf16(a0, Bf[0][1][0], accA1, 0, 0, 0);
    accA1 = __builtin_amdgcn_mfma_f32_16x16x32_bf16(a1, Bf[0][1][1], accA1, 0, 0, 0);
    accB0 = __builtin_amdgcn_mfma_f32_16x16x32_bf16(a0, Bf[1][0][0], accB0, 0, 0, 0);
    accB0 = __builtin_amdgcn_mfma_f32_16x16x32_bf16(a1, Bf[1][0][1], accB0, 0, 0, 0);
    accB1 = __builtin_amdgcn_mfma_f32_16x16x32_bf16(a0, Bf[1][1][0], accB1, 0, 0, 0);
    accB1 = __builtin_amdgcn_mfma_f32_16x16x32_bf16(a1, Bf[1][1][1], accB1, 0, 0, 0);

#pragma unroll
    for (int j = 0; j < 4; ++j) {
        const long long node = base + g * 4 + j;
        if (node < N) {
            ya[node * 32 + n]      = q8(accA0[j]);
            ya[node * 32 + 16 + n] = q8(accA1[j]);
            yb[node * 32 + n]      = q8(accB0[j]);
            yb[node * 32 + 16 + n] = q8(accB1[j]);
        }
    }
}

// ---------------- main: persistent pipelined per-edge kernel (E%64==0) ------
__global__ __launch_bounds__(256, 6) void edge_mlp_v7(
    const char* __restrict__ ya, const char* __restrict__ yb,
    const int* __restrict__ ei,
    const float* __restrict__ W2, const float* __restrict__ b2,
    const float* __restrict__ W3, const float* __restrict__ b3,
    const float* __restrict__ temp,
    float* __restrict__ out, int E)
{
    const int t = threadIdx.x;
    const int l = t & 63, n = l & 15, g = l >> 4;
    const int nW = gridDim.x << 2;                 // total waves
    const int tile0 = (blockIdx.x << 2) + (t >> 6);
    const int nTiles = E >> 6;                     // 64-edge tiles
    if (tile0 >= nTiles) return;

    // W2 as the A operand: lane (g,n) elem j = W2[row n][k g*8+j]
    const short8v W2f = conv8(W2 + n * 32 + g * 8);
    const f32x4 b2v4 = *(const f32x4*)(b2 + g * 4);
    const f32x4 w3v4 = *(const f32x4*)(W3 + g * 4);
    const float b3v  = b3[0];
    const float invT = 1.0f / temp[0];
    const int goff = g * 8;

#define LDIDX(tt, rn, cn) do { const int _b = (tt) << 6;                      \
    _Pragma("unroll") for (int st = 0; st < 4; ++st) {                        \
        rn[st] = ei[_b + st * 16 + n];                                        \
        cn[st] = ei[E + _b + st * 16 + n]; } } while (0)

#define LDGAT(rn, cn, qa, qb) do {                                            \
    _Pragma("unroll") for (int st = 0; st < 4; ++st) {                        \
        qa[st] = *(const char8v*)(ya + rn[st] * 32 + goff);                   \
        qb[st] = *(const char8v*)(yb + cn[st] * 32 + goff); } } while (0)

#define COMPUTE(tt, qa, qb) do { const int _base = (tt) << 6;                 \
    _Pragma("unroll") for (int st = 0; st < 4; ++st) {                        \
        short8v hv;                                                           \
        _Pragma("unroll") for (int j = 0; j < 8; ++j) {                       \
            const int si = (int)qa[st][j] + (int)qb[st][j];                   \
            hv[j] = (short)f32_bf16(fmaxf((float)si * QDEQ, 0.0f)); }         \
        f32x4 acc = {0.f, 0.f, 0.f, 0.f};                                     \
        acc = __builtin_amdgcn_mfma_f32_16x16x32_bf16(W2f, hv, acc, 0, 0, 0); \
        float s_ = 0.0f;                                                      \
        _Pragma("unroll") for (int j = 0; j < 4; ++j)                         \
            s_ += w3v4[j] * fmaxf(acc[j] + b2v4[j], 0.0f);                    \
        s_ += __shfl_xor(s_, 16);                                             \
        s_ += __shfl_xor(s_, 32);                                             \
        if (l < 16) {                                                         \
            const float ew = 1.0f / (1.0f + __expf(-(s_ + b3v)));             \
            out[_base + st * 16 + l] = 1.0f / (1.0f + __expf(-ew * invT)); }  \
    } } while (0)

    // ---- 3-stage pipeline: idx 2 ahead, gathers 1 ahead, compute current ----
    int rnA[4], cnA[4], rnB[4], cnB[4];
    char8v qaA[4], qbA[4], qaB[4], qbB[4];

    int tA = tile0;
    int tB = tA + nW;
    bool hB = tB < nTiles;
    LDIDX(tA, rnA, cnA);
    if (hB) LDIDX(tB, rnB, cnB);
    LDGAT(rnA, cnA, qaA, qbA);

    for (;;) {
        // phase A: compute tA (A gathers); prefetch gathers tB, idx tC
        const int tC = tB + nW;
        const bool hC = hB && (tC < nTiles);
        if (hB) LDGAT(rnB, cnB, qaB, qbB);
        if (hC) LDIDX(tC, rnA, cnA);          // rnA free (gather issued)
        COMPUTE(tA, qaA, qbA);
        if (!hB) return;

        // phase B: compute tB (B gathers); prefetch gathers tC, idx tD
        const int tD = tC + nW;
        const bool hD = hC && (tD < nTiles);
        if (hC) LDGAT(rnA, cnA, qaA, qbA);
        if (hD) LDIDX(tD, rnB, cnB);
        COMPUTE(tB, qaB, qbB);
        if (!hC) return;

        tA = tC; tB = tD; hB = hD;
    }
#undef LDIDX
#undef LDGAT
#undef COMPUTE
}

// ---------------- tail variant (E % 64 != 0): clamped per-block kernel ------
__global__ __launch_bounds__(256, 8) void edge_mlp_tail(
    const char* __restrict__ ya, const char* __restrict__ yb,
    const int* __restrict__ ei,
    const float* __restrict__ W2, const float* __restrict__ b2,
    const float* __restrict__ W3, const float* __restrict__ b3,
    const float* __restrict__ temp,
    float* __restrict__ out, int E)
{
    const int t = threadIdx.x;
    const int w = t >> 6, l = t & 63, n = l & 15, g = l >> 4;

    const short8v W2f = conv8(W2 + n * 32 + g * 8);
    const f32x4 b2v4 = *(const f32x4*)(b2 + g * 4);
    const f32x4 w3v4 = *(const f32x4*)(W3 + g * 4);
    const float b3v  = b3[0];
    const float invT = 1.0f / temp[0];

    const int eb = blockIdx.x * 256 + w * 64;

    int rn_[4], cn_[4];
#pragma unroll
    for (int it = 0; it < 4; ++it) {
        int e  = eb + it * 16 + n;
        int ec = (e < E) ? e : (E - 1);
        rn_[it] = ei[ec];
        cn_[it] = ei[(size_t)E + ec];
    }
    char8v qa[4], qb[4];
#pragma unroll
    for (int it = 0; it < 4; ++it) {
        qa[it] = *(const char8v*)(ya + (rn_[it] * 32 + g * 8));
        qb[it] = *(const char8v*)(yb + (cn_[it] * 32 + g * 8));
    }
#pragma unroll
    for (int it = 0; it < 4; ++it) {
        const int base = eb + it * 16;
        short8v hv;
#pragma unroll
        for (int j = 0; j < 8; ++j) {
            const int si = (int)qa[it][j] + (int)qb[it][j];
            hv[j] = (short)f32_bf16(fmaxf((float)si * QDEQ, 0.0f));
        }
        f32x4 acc = {0.f, 0.f, 0.f, 0.f};
        acc = __builtin_amdgcn_mfma_f32_16x16x32_bf16(W2f, hv, acc, 0, 0, 0);
        float s = 0.0f;
#pragma unroll
        for (int j = 0; j < 4; ++j)
            s += w3v4[j] * fmaxf(acc[j] + b2v4[j], 0.0f);
        s += __shfl_xor(s, 16);
        s += __shfl_xor(s, 32);
        if (l < 16) {
            const int eo = base + l;
            if (eo < E) {
                const float ew = 1.0f / (1.0f + __expf(-(s + b3v)));
                out[eo] = 1.0f / (1.0f + __expf(-ew * invT));
            }
        }
    }
}

// ---------------- fallback (ws too small): direct per-edge path -------------
__global__ __launch_bounds__(256, 4) void edge_mlp_direct(
    const float* __restrict__ x, const int* __restrict__ ei,
    const float* __restrict__ W1, const float* __restrict__ b1,
    const float* __restrict__ W2, const float* __restrict__ b2,
    const float* __restrict__ W3, const float* __restrict__ b3,
    const float* __restrict__ temp,
    float* __restrict__ out, int E)
{
    __shared__ short h1lds[4][16 * 40];
    const int t = threadIdx.x;
    const int w = t >> 6, l = t & 63, n = l & 15, g = l >> 4;

    short8v B1f[2][4];
#pragma unroll
    for (int nt = 0; nt < 2; ++nt)
#pragma unroll
        for (int q = 0; q < 4; ++q)
            B1f[nt][q] = conv8(W1 + ((nt * 16 + n) * 128 + q * 32 + g * 8));
    const short8v B2f = conv8(W2 + n * 32 + g * 8);

    const float b1v0 = b1[n], b1v1 = b1[16 + n];
    const float b2v = b2[n], w3v = W3[n], b3v = b3[0];
    const float invT = 1.0f / temp[0];

    short* hl = &h1lds[w][0];
    const long long eb = (long long)blockIdx.x * 256 + (long long)w * 64;

    for (int it = 0; it < 4; ++it) {
        const long long base = eb + it * 16;
        if (base >= E) break;
        long long e  = base + n;
        long long ec = (e < E) ? e : (long long)(E - 1);
        const int rn = ei[ec];
        const int cn = ei[(size_t)E + ec];

        f32x4 acc0 = {0.f,0.f,0.f,0.f}, acc1 = {0.f,0.f,0.f,0.f};
#pragma unroll
        for (int q = 0; q < 4; ++q) {
            const int node = (q < 2) ? rn : cn;
            const int elem = ((q & 1) * 32) + g * 8;
            short8v a = conv8(x + ((long long)node * 64 + elem));
            acc0 = __builtin_amdgcn_mfma_f32_16x16x32_bf16(a, B1f[0][q], acc0, 0, 0, 0);
            acc1 = __builtin_amdgcn_mfma_f32_16x16x32_bf16(a, B1f[1][q], acc1, 0, 0, 0);
        }
#pragma unroll
        for (int j = 0; j < 4; ++j) {
            const int m = g * 4 + j;
            hl[m * 40 + n]      = (short)f32_bf16(fmaxf(acc0[j] + b1v0, 0.f));
            hl[m * 40 + 16 + n] = (short)f32_bf16(fmaxf(acc1[j] + b1v1, 0.f));
        }
        const short8v a2 = *(const short8v*)(hl + ((l & 15) * 40 + g * 8));
        f32x4 acc2 = {0.f,0.f,0.f,0.f};
        acc2 = __builtin_amdgcn_mfma_f32_16x16x32_bf16(a2, B2f, acc2, 0, 0, 0);

        float p0 = w3v * fmaxf(acc2[0] + b2v, 0.f);
        float p1 = w3v * fmaxf(acc2[1] + b2v, 0.f);
        float p2 = w3v * fmaxf(acc2[2] + b2v, 0.f);
        float p3 = w3v * fmaxf(acc2[3] + b2v, 0.f);
#pragma unroll
        for (int mask = 1; mask <= 8; mask <<= 1) {
            p0 += __shfl_xor(p0, mask, 16);
            p1 += __shfl_xor(p1, mask, 16);
            p2 += __shfl_xor(p2, mask, 16);
            p3 += __shfl_xor(p3, mask, 16);
        }
        if (n < 4) {
            const float pv = (n == 0) ? p0 : ((n == 1) ? p1 : ((n == 2) ? p2 : p3));
            const float ew = 1.0f / (1.0f + __expf(-(pv + b3v)));
            const float o  = 1.0f / (1.0f + __expf(-ew * invT));
            const long long eo = base + g * 4 + n;
            if (eo < E) out[eo] = o;
        }
    }
}

extern "C" void kernel_launch(void* const* d_in, const int* in_sizes, int n_in,
                              void* d_out, int out_size, void* d_ws, size_t ws_size,
                              hipStream_t stream)
{
    const float* x    = (const float*)d_in[0];
    const int*   ei   = (const int*)  d_in[1];
    const float* W1   = (const float*)d_in[2];
    const float* b1   = (const float*)d_in[3];
    const float* W2   = (const float*)d_in[4];
    const float* b2   = (const float*)d_in[5];
    const float* W3   = (const float*)d_in[6];
    const float* b3   = (const float*)d_in[7];
    const float* temp = (const float*)d_in[8];
    float* out = (float*)d_out;

    const int E = in_sizes[1] / 2;        // edge_index is [2, E]
    const int N = in_sizes[0] / 64;       // nodes
    const size_t need = (size_t)N * 64;   // ya + yb, int8 [N][32] each

    if (ws_size >= need) {
        char* yat = (char*)d_ws;
        char* ybt = yat + (size_t)N * 32;
        precompute_y<<<(N + 63) / 64, 256, 0, stream>>>(x, W1, b1, yat, ybt, N);
        if (E % 64 == 0) {
            const int nTiles = E / 64;
            int blocks = (nTiles + 3) / 4;
            if (blocks > 1536) blocks = 1536;   // 6144 persistent waves
            edge_mlp_v7<<<blocks, 256, 0, stream>>>(
                yat, ybt, ei, W2, b2, W3, b3, temp, out, E);
        } else {
            edge_mlp_tail<<<(E + 255) / 256, 256, 0, stream>>>(
                yat, ybt, ei, W2, b2, W3, b3, temp, out, E);
        }
    } else {
        edge_mlp_direct<<<(E + 255) / 256, 256, 0, stream>>>(
            x, ei, W1, b1, W2, b2, W3, b3, temp, out, E);
    }
}

// Round 8
// 49.063 us; speedup vs baseline: 2.5480x; 2.5480x over previous
//
#include <hip/hip_runtime.h>

// DynamicEdgeWeightLearner — v8: tables hosted in d_out (cacheability probe).
//   h1 = relu(W1a@x[row] + W1b@x[col] + b1),  W1 = [W1a | W1b]
// Evidence (r7): gathers from d_ws show FETCH = 225 MB = full miss (0% cache
// absorption) while v3's gathers from d_in were 89% absorbed -> d_ws scratch
// appears non-L2-cacheable. v8 probes this: int8 node tables (ya|yb, 3.2 MB)
// are written into d_out (6.4 MB) by precompute; the main kernel (v5/v6
// structure, fastest measured; nontemporal hints reverted per r6) gathers
// from d_out and streams results to d_ws; a final 6.4 MB D2D memcpy puts
// results into d_out.
// Main kernel per 64-edge wave-tile: gather qa[row],qb[col] (8 B/lane),
// h1 = relu((qa+qb)*s) -> bf16 B-frag, swapped MFMA (C[ch][edge]),
// 2 shfl_xor reduce, coalesced 16-float store.

typedef __attribute__((ext_vector_type(8))) short short8v;  // 8 x bf16
typedef __attribute__((ext_vector_type(8))) char  char8v;   // 8 x int8
typedef __attribute__((ext_vector_type(4))) float f32x4;    // MFMA C/D frag

#define QSCALE   63.5f           // 127 / 2.0
#define QDEQ     0.015748031f    // 1 / 63.5

__device__ __forceinline__ unsigned short f32_bf16(float f) {
    union { float f; unsigned u; } v; v.f = f;
    return (unsigned short)((v.u + 0x7fffu + ((v.u >> 16) & 1u)) >> 16);  // RTNE
}
__device__ __forceinline__ short8v conv8(const float* src) {
    f32x4 f0 = *(const f32x4*)src;
    f32x4 f1 = *(const f32x4*)(src + 4);
    short8v r;
#pragma unroll
    for (int j = 0; j < 4; ++j) {
        r[j]     = (short)f32_bf16(f0[j]);
        r[4 + j] = (short)f32_bf16(f1[j]);
    }
    return r;
}
__device__ __forceinline__ char q8(float y) {
    int q = __float2int_rn(y * QSCALE);
    q = q > 127 ? 127 : (q < -127 ? -127 : q);
    return (char)q;
}

// ---------------- precompute: int8 ya = x@W1a^T + b1, yb = x@W1b^T ----------
__global__ __launch_bounds__(256) void precompute_y(
    const float* __restrict__ x, const float* __restrict__ W1,
    const float* __restrict__ b1,
    char* __restrict__ ya, char* __restrict__ yb, int N)
{
    const int t = threadIdx.x;
    const int w = t >> 6, l = t & 63, n = l & 15, g = l >> 4;
    const long long base = ((long long)blockIdx.x * 4 + w) * 16;
    if (base >= N) return;

    short8v Bf[2][2][2];
#pragma unroll
    for (int s = 0; s < 2; ++s)
#pragma unroll
        for (int nt = 0; nt < 2; ++nt)
#pragma unroll
            for (int q = 0; q < 2; ++q)
                Bf[s][nt][q] = conv8(W1 + (nt * 16 + n) * 128 + s * 64 + q * 32 + g * 8);

    long long row = base + n; if (row > (long long)N - 1) row = N - 1;
    const float* xr = x + row * 64;
    short8v a0 = conv8(xr + g * 8);
    short8v a1 = conv8(xr + 32 + g * 8);

    const float bA0 = b1[n], bA1 = b1[16 + n];
    f32x4 accA0 = {bA0, bA0, bA0, bA0};
    f32x4 accA1 = {bA1, bA1, bA1, bA1};
    f32x4 accB0 = {0.f, 0.f, 0.f, 0.f};
    f32x4 accB1 = {0.f, 0.f, 0.f, 0.f};

    accA0 = __builtin_amdgcn_mfma_f32_16x16x32_bf16(a0, Bf[0][0][0], accA0, 0, 0, 0);
    accA0 = __builtin_amdgcn_mfma_f32_16x16x32_bf16(a1, Bf[0][0][1], accA0, 0, 0, 0);
    accA1 = __builtin_amdgcn_mfma_f32_16x16x32_bf16(a0, Bf[0][1][0], accA1, 0, 0, 0);
    accA1 = __builtin_amdgcn_mfma_f32_16x16x32_bf16(a1, Bf[0][1][1], accA1, 0, 0, 0);
    accB0 = __builtin_amdgcn_mfma_f32_16x16x32_bf16(a0, Bf[1][0][0], accB0, 0, 0, 0);
    accB0 = __builtin_amdgcn_mfma_f32_16x16x32_bf16(a1, Bf[1][0][1], accB0, 0, 0, 0);
    accB1 = __builtin_amdgcn_mfma_f32_16x16x32_bf16(a0, Bf[1][1][0], accB1, 0, 0, 0);
    accB1 = __builtin_amdgcn_mfma_f32_16x16x32_bf16(a1, Bf[1][1][1], accB1, 0, 0, 0);

#pragma unroll
    for (int j = 0; j < 4; ++j) {
        const long long node = base + g * 4 + j;
        if (node < N) {
            ya[node * 32 + n]      = q8(accA0[j]);
            ya[node * 32 + 16 + n] = q8(accA1[j]);
            yb[node * 32 + n]      = q8(accB0[j]);
            yb[node * 32 + 16 + n] = q8(accB1[j]);
        }
    }
}

// ---------------- main: per-edge fused layers 1(add)+2(MFMA)+3 -------------
// v5 structure exactly (fastest measured): per block 4 waves x 64 edges,
// all index loads + gathers issued up-front, then 4 compute sub-tiles.
template<bool EXACT>
__global__ __launch_bounds__(256, 8) void edge_mlp_v8(
    const char* __restrict__ ya, const char* __restrict__ yb,
    const int* __restrict__ ei,
    const float* __restrict__ W2, const float* __restrict__ b2,
    const float* __restrict__ W3, const float* __restrict__ b3,
    const float* __restrict__ temp,
    float* __restrict__ res, int E)
{
    const int t = threadIdx.x;
    const int w = t >> 6, l = t & 63, n = l & 15, g = l >> 4;

    // W2 as the A operand: lane (g,n) elem j = W2[row n][k g*8+j]
    const short8v W2f = conv8(W2 + n * 32 + g * 8);
    const f32x4 b2v4 = *(const f32x4*)(b2 + g * 4);
    const f32x4 w3v4 = *(const f32x4*)(W3 + g * 4);
    const float b3v  = b3[0];
    const float invT = 1.0f / temp[0];

    const int eb = blockIdx.x * 256 + w * 64;

    // hoisted index loads (8 independent, coalesced/broadcast)
    int rn_[4], cn_[4];
#pragma unroll
    for (int it = 0; it < 4; ++it) {
        if constexpr (EXACT) {
            rn_[it] = ei[eb + it * 16 + n];
            cn_[it] = ei[E + eb + it * 16 + n];
        } else {
            int e  = eb + it * 16 + n;
            int ec = (e < E) ? e : (E - 1);
            rn_[it] = ei[ec];
            cn_[it] = ei[(size_t)E + ec];
        }
    }

    // all 8 gathers issued up-front (8 B/lane; 32 B per node row)
    char8v qa[4], qb[4];
#pragma unroll
    for (int it = 0; it < 4; ++it) {
        qa[it] = *(const char8v*)(ya + (rn_[it] * 32 + g * 8));
        qb[it] = *(const char8v*)(yb + (cn_[it] * 32 + g * 8));
    }

#pragma unroll
    for (int it = 0; it < 4; ++it) {
        const int base = eb + it * 16;

        // h1 = relu((qa+qb) * s); lane (g,n) elem j = h1[edge n][ch g*8+j]
        short8v hB;
#pragma unroll
        for (int j = 0; j < 8; ++j) {
            const int   si = (int)qa[it][j] + (int)qb[it][j];
            const float h  = fmaxf((float)si * QDEQ, 0.0f);
            hB[j] = (short)f32_bf16(h);
        }

        // layer 2 swapped: C[row=out_ch][col=edge]; lane (g,n): C[g*4+j][n]
        f32x4 acc2 = {0.f, 0.f, 0.f, 0.f};
        acc2 = __builtin_amdgcn_mfma_f32_16x16x32_bf16(W2f, hB, acc2, 0, 0, 0);

        // layer 3: partial over this lane's 4 channels, then reduce over g
        float s = 0.0f;
#pragma unroll
        for (int j = 0; j < 4; ++j)
            s += w3v4[j] * fmaxf(acc2[j] + b2v4[j], 0.0f);
        s += __shfl_xor(s, 16);
        s += __shfl_xor(s, 32);

        if (l < 16) {
            const int eo = base + l;
            const float ew = 1.0f / (1.0f + __expf(-(s + b3v)));
            const float o  = 1.0f / (1.0f + __expf(-ew * invT));
            if constexpr (EXACT) {
                res[eo] = o;
            } else {
                if (eo < E) res[eo] = o;
            }
        }
    }
}

// ---------------- fallback (buffers too small): direct per-edge path --------
__global__ __launch_bounds__(256, 4) void edge_mlp_direct(
    const float* __restrict__ x, const int* __restrict__ ei,
    const float* __restrict__ W1, const float* __restrict__ b1,
    const float* __restrict__ W2, const float* __restrict__ b2,
    const float* __restrict__ W3, const float* __restrict__ b3,
    const float* __restrict__ temp,
    float* __restrict__ out, int E)
{
    __shared__ short h1lds[4][16 * 40];
    const int t = threadIdx.x;
    const int w = t >> 6, l = t & 63, n = l & 15, g = l >> 4;

    short8v B1f[2][4];
#pragma unroll
    for (int nt = 0; nt < 2; ++nt)
#pragma unroll
        for (int q = 0; q < 4; ++q)
            B1f[nt][q] = conv8(W1 + ((nt * 16 + n) * 128 + q * 32 + g * 8));
    const short8v B2f = conv8(W2 + n * 32 + g * 8);

    const float b1v0 = b1[n], b1v1 = b1[16 + n];
    const float b2v = b2[n], w3v = W3[n], b3v = b3[0];
    const float invT = 1.0f / temp[0];

    short* hl = &h1lds[w][0];
    const long long eb = (long long)blockIdx.x * 256 + (long long)w * 64;

    for (int it = 0; it < 4; ++it) {
        const long long base = eb + it * 16;
        if (base >= E) break;
        long long e  = base + n;
        long long ec = (e < E) ? e : (long long)(E - 1);
        const int rn = ei[ec];
        const int cn = ei[(size_t)E + ec];

        f32x4 acc0 = {0.f,0.f,0.f,0.f}, acc1 = {0.f,0.f,0.f,0.f};
#pragma unroll
        for (int q = 0; q < 4; ++q) {
            const int node = (q < 2) ? rn : cn;
            const int elem = ((q & 1) * 32) + g * 8;
            short8v a = conv8(x + ((long long)node * 64 + elem));
            acc0 = __builtin_amdgcn_mfma_f32_16x16x32_bf16(a, B1f[0][q], acc0, 0, 0, 0);
            acc1 = __builtin_amdgcn_mfma_f32_16x16x32_bf16(a, B1f[1][q], acc1, 0, 0, 0);
        }
#pragma unroll
        for (int j = 0; j < 4; ++j) {
            const int m = g * 4 + j;
            hl[m * 40 + n]      = (short)f32_bf16(fmaxf(acc0[j] + b1v0, 0.f));
            hl[m * 40 + 16 + n] = (short)f32_bf16(fmaxf(acc1[j] + b1v1, 0.f));
        }
        const short8v a2 = *(const short8v*)(hl + ((l & 15) * 40 + g * 8));
        f32x4 acc2 = {0.f,0.f,0.f,0.f};
        acc2 = __builtin_amdgcn_mfma_f32_16x16x32_bf16(a2, B2f, acc2, 0, 0, 0);

        float p0 = w3v * fmaxf(acc2[0] + b2v, 0.f);
        float p1 = w3v * fmaxf(acc2[1] + b2v, 0.f);
        float p2 = w3v * fmaxf(acc2[2] + b2v, 0.f);
        float p3 = w3v * fmaxf(acc2[3] + b2v, 0.f);
#pragma unroll
        for (int mask = 1; mask <= 8; mask <<= 1) {
            p0 += __shfl_xor(p0, mask, 16);
            p1 += __shfl_xor(p1, mask, 16);
            p2 += __shfl_xor(p2, mask, 16);
            p3 += __shfl_xor(p3, mask, 16);
        }
        if (n < 4) {
            const float pv = (n == 0) ? p0 : ((n == 1) ? p1 : ((n == 2) ? p2 : p3));
            const float ew = 1.0f / (1.0f + __expf(-(pv + b3v)));
            const float o  = 1.0f / (1.0f + __expf(-ew * invT));
            const long long eo = base + g * 4 + n;
            if (eo < E) out[eo] = o;
        }
    }
}

extern "C" void kernel_launch(void* const* d_in, const int* in_sizes, int n_in,
                              void* d_out, int out_size, void* d_ws, size_t ws_size,
                              hipStream_t stream)
{
    const float* x    = (const float*)d_in[0];
    const int*   ei   = (const int*)  d_in[1];
    const float* W1   = (const float*)d_in[2];
    const float* b1   = (const float*)d_in[3];
    const float* W2   = (const float*)d_in[4];
    const float* b2   = (const float*)d_in[5];
    const float* W3   = (const float*)d_in[6];
    const float* b3   = (const float*)d_in[7];
    const float* temp = (const float*)d_in[8];
    float* out = (float*)d_out;

    const int E = in_sizes[1] / 2;            // edge_index is [2, E]
    const int N = in_sizes[0] / 64;           // nodes
    const size_t tabBytes = (size_t)N * 64;   // ya + yb, int8 [N][32] each
    const size_t outBytes = (size_t)E * 4;

    const int eblocks = (E + 255) / 256;
    const int pblocks = (N + 63) / 64;

    if ((size_t)out_size * 4 >= tabBytes && ws_size >= outBytes) {
        // Tables live in d_out (probe: normal cacheable allocation?);
        // results stream to d_ws, then D2D copy back into d_out.
        char*  yat = (char*)d_out;
        char*  ybt = yat + (size_t)N * 32;
        float* res = (float*)d_ws;
        precompute_y<<<pblocks, 256, 0, stream>>>(x, W1, b1, yat, ybt, N);
        if (E % 256 == 0) {
            edge_mlp_v8<true><<<eblocks, 256, 0, stream>>>(
                yat, ybt, ei, W2, b2, W3, b3, temp, res, E);
        } else {
            edge_mlp_v8<false><<<eblocks, 256, 0, stream>>>(
                yat, ybt, ei, W2, b2, W3, b3, temp, res, E);
        }
        hipMemcpyAsync(d_out, d_ws, outBytes, hipMemcpyDeviceToDevice, stream);
    } else if (ws_size >= tabBytes) {
        // v5 arrangement: tables in d_ws, write d_out directly.
        char* yat = (char*)d_ws;
        char* ybt = yat + (size_t)N * 32;
        precompute_y<<<pblocks, 256, 0, stream>>>(x, W1, b1, yat, ybt, N);
        if (E % 256 == 0) {
            edge_mlp_v8<true><<<eblocks, 256, 0, stream>>>(
                yat, ybt, ei, W2, b2, W3, b3, temp, out, E);
        } else {
            edge_mlp_v8<false><<<eblocks, 256, 0, stream>>>(
                yat, ybt, ei, W2, b2, W3, b3, temp, out, E);
        }
    } else {
        edge_mlp_direct<<<eblocks, 256, 0, stream>>>(
            x, ei, W1, b1, W2, b2, W3, b3, temp, out, E);
    }
}

// Round 9
// 44.740 us; speedup vs baseline: 2.7942x; 1.0966x over previous
//
#include <hip/hip_runtime.h>

// DynamicEdgeWeightLearner — v9: restore measured-best v5 arrangement.
//   h1 = relu(W1a@x[row] + W1b@x[col] + b1),  W1 = [W1a | W1b]
// Precompute per node (MFMA): ya = x@W1a^T + b1, yb = x@W1b^T, int8
// (scale 127/2, clamp +-2) in d_ws. Main kernel per 64-edge wave-tile:
// gather qa[row],qb[col] (8 B/lane), h1 = relu((qa+qb)*s) -> bf16 B-frag,
// swapped MFMA (C[ch][edge]), 2 shfl_xor reduce, coalesced 16-float store
// straight to d_out.
// Evidence ledger: r6 nontemporal hints -5us (reverted); r7 persistent
// pipeline -75us (reverted); r8 d_out-hosted tables -4us (reverted) — r8
// also refuted the d_ws-uncacheable theory. Traffic is line-granular
// compulsory: 2 x 64B line-touches/edge = 205 MB + 19 MB streams = 225 MB
// (r7 FETCH confirms); v5 runs it at ~5.9 TB/s ≈ 90% of achieved fill BW
// -> within ~10% of the random-line fabric roofline.

typedef __attribute__((ext_vector_type(8))) short short8v;  // 8 x bf16
typedef __attribute__((ext_vector_type(8))) char  char8v;   // 8 x int8
typedef __attribute__((ext_vector_type(4))) float f32x4;    // MFMA C/D frag

#define QSCALE   63.5f           // 127 / 2.0
#define QDEQ     0.015748031f    // 1 / 63.5

__device__ __forceinline__ unsigned short f32_bf16(float f) {
    union { float f; unsigned u; } v; v.f = f;
    return (unsigned short)((v.u + 0x7fffu + ((v.u >> 16) & 1u)) >> 16);  // RTNE
}
__device__ __forceinline__ short8v conv8(const float* src) {
    f32x4 f0 = *(const f32x4*)src;
    f32x4 f1 = *(const f32x4*)(src + 4);
    short8v r;
#pragma unroll
    for (int j = 0; j < 4; ++j) {
        r[j]     = (short)f32_bf16(f0[j]);
        r[4 + j] = (short)f32_bf16(f1[j]);
    }
    return r;
}
__device__ __forceinline__ char q8(float y) {
    int q = __float2int_rn(y * QSCALE);
    q = q > 127 ? 127 : (q < -127 ? -127 : q);
    return (char)q;
}

// ---------------- precompute: int8 ya = x@W1a^T + b1, yb = x@W1b^T ----------
__global__ __launch_bounds__(256) void precompute_y(
    const float* __restrict__ x, const float* __restrict__ W1,
    const float* __restrict__ b1,
    char* __restrict__ ya, char* __restrict__ yb, int N)
{
    const int t = threadIdx.x;
    const int w = t >> 6, l = t & 63, n = l & 15, g = l >> 4;
    const long long base = ((long long)blockIdx.x * 4 + w) * 16;
    if (base >= N) return;

    short8v Bf[2][2][2];
#pragma unroll
    for (int s = 0; s < 2; ++s)
#pragma unroll
        for (int nt = 0; nt < 2; ++nt)
#pragma unroll
            for (int q = 0; q < 2; ++q)
                Bf[s][nt][q] = conv8(W1 + (nt * 16 + n) * 128 + s * 64 + q * 32 + g * 8);

    long long row = base + n; if (row > (long long)N - 1) row = N - 1;
    const float* xr = x + row * 64;
    short8v a0 = conv8(xr + g * 8);
    short8v a1 = conv8(xr + 32 + g * 8);

    const float bA0 = b1[n], bA1 = b1[16 + n];
    f32x4 accA0 = {bA0, bA0, bA0, bA0};
    f32x4 accA1 = {bA1, bA1, bA1, bA1};
    f32x4 accB0 = {0.f, 0.f, 0.f, 0.f};
    f32x4 accB1 = {0.f, 0.f, 0.f, 0.f};

    accA0 = __builtin_amdgcn_mfma_f32_16x16x32_bf16(a0, Bf[0][0][0], accA0, 0, 0, 0);
    accA0 = __builtin_amdgcn_mfma_f32_16x16x32_bf16(a1, Bf[0][0][1], accA0, 0, 0, 0);
    accA1 = __builtin_amdgcn_mfma_f32_16x16x32_bf16(a0, Bf[0][1][0], accA1, 0, 0, 0);
    accA1 = __builtin_amdgcn_mfma_f32_16x16x32_bf16(a1, Bf[0][1][1], accA1, 0, 0, 0);
    accB0 = __builtin_amdgcn_mfma_f32_16x16x32_bf16(a0, Bf[1][0][0], accB0, 0, 0, 0);
    accB0 = __builtin_amdgcn_mfma_f32_16x16x32_bf16(a1, Bf[1][0][1], accB0, 0, 0, 0);
    accB1 = __builtin_amdgcn_mfma_f32_16x16x32_bf16(a0, Bf[1][1][0], accB1, 0, 0, 0);
    accB1 = __builtin_amdgcn_mfma_f32_16x16x32_bf16(a1, Bf[1][1][1], accB1, 0, 0, 0);

#pragma unroll
    for (int j = 0; j < 4; ++j) {
        const long long node = base + g * 4 + j;
        if (node < N) {
            ya[node * 32 + n]      = q8(accA0[j]);
            ya[node * 32 + 16 + n] = q8(accA1[j]);
            yb[node * 32 + n]      = q8(accB0[j]);
            yb[node * 32 + 16 + n] = q8(accB1[j]);
        }
    }
}

// ---------------- main: per-edge fused layers 1(add)+2(MFMA)+3 -------------
template<bool EXACT>
__global__ __launch_bounds__(256, 8) void edge_mlp_v9(
    const char* __restrict__ ya, const char* __restrict__ yb,
    const int* __restrict__ ei,
    const float* __restrict__ W2, const float* __restrict__ b2,
    const float* __restrict__ W3, const float* __restrict__ b3,
    const float* __restrict__ temp,
    float* __restrict__ out, int E)
{
    const int t = threadIdx.x;
    const int w = t >> 6, l = t & 63, n = l & 15, g = l >> 4;

    // W2 as the A operand: lane (g,n) elem j = W2[row n][k g*8+j]
    const short8v W2f = conv8(W2 + n * 32 + g * 8);
    const f32x4 b2v4 = *(const f32x4*)(b2 + g * 4);
    const f32x4 w3v4 = *(const f32x4*)(W3 + g * 4);
    const float b3v  = b3[0];
    const float invT = 1.0f / temp[0];

    const int eb = blockIdx.x * 256 + w * 64;

    // hoisted index loads (8 independent, coalesced/broadcast)
    int rn_[4], cn_[4];
#pragma unroll
    for (int it = 0; it < 4; ++it) {
        if constexpr (EXACT) {
            rn_[it] = ei[eb + it * 16 + n];
            cn_[it] = ei[E + eb + it * 16 + n];
        } else {
            int e  = eb + it * 16 + n;
            int ec = (e < E) ? e : (E - 1);
            rn_[it] = ei[ec];
            cn_[it] = ei[(size_t)E + ec];
        }
    }

    // all 8 gathers issued up-front (8 B/lane; 32 B per node row)
    char8v qa[4], qb[4];
#pragma unroll
    for (int it = 0; it < 4; ++it) {
        qa[it] = *(const char8v*)(ya + (rn_[it] * 32 + g * 8));
        qb[it] = *(const char8v*)(yb + (cn_[it] * 32 + g * 8));
    }

#pragma unroll
    for (int it = 0; it < 4; ++it) {
        const int base = eb + it * 16;

        // h1 = relu((qa+qb) * s); lane (g,n) elem j = h1[edge n][ch g*8+j]
        short8v hB;
#pragma unroll
        for (int j = 0; j < 8; ++j) {
            const int   si = (int)qa[it][j] + (int)qb[it][j];
            const float h  = fmaxf((float)si * QDEQ, 0.0f);
            hB[j] = (short)f32_bf16(h);
        }

        // layer 2 swapped: C[row=out_ch][col=edge]; lane (g,n): C[g*4+j][n]
        f32x4 acc2 = {0.f, 0.f, 0.f, 0.f};
        acc2 = __builtin_amdgcn_mfma_f32_16x16x32_bf16(W2f, hB, acc2, 0, 0, 0);

        // layer 3: partial over this lane's 4 channels, then reduce over g
        float s = 0.0f;
#pragma unroll
        for (int j = 0; j < 4; ++j)
            s += w3v4[j] * fmaxf(acc2[j] + b2v4[j], 0.0f);
        s += __shfl_xor(s, 16);
        s += __shfl_xor(s, 32);

        if (l < 16) {
            const int eo = base + l;
            const float ew = 1.0f / (1.0f + __expf(-(s + b3v)));
            const float o  = 1.0f / (1.0f + __expf(-ew * invT));
            if constexpr (EXACT) {
                out[eo] = o;
            } else {
                if (eo < E) out[eo] = o;
            }
        }
    }
}

// ---------------- fallback (ws too small): direct per-edge path -------------
__global__ __launch_bounds__(256, 4) void edge_mlp_direct(
    const float* __restrict__ x, const int* __restrict__ ei,
    const float* __restrict__ W1, const float* __restrict__ b1,
    const float* __restrict__ W2, const float* __restrict__ b2,
    const float* __restrict__ W3, const float* __restrict__ b3,
    const float* __restrict__ temp,
    float* __restrict__ out, int E)
{
    __shared__ short h1lds[4][16 * 40];
    const int t = threadIdx.x;
    const int w = t >> 6, l = t & 63, n = l & 15, g = l >> 4;

    short8v B1f[2][4];
#pragma unroll
    for (int nt = 0; nt < 2; ++nt)
#pragma unroll
        for (int q = 0; q < 4; ++q)
            B1f[nt][q] = conv8(W1 + ((nt * 16 + n) * 128 + q * 32 + g * 8));
    const short8v B2f = conv8(W2 + n * 32 + g * 8);

    const float b1v0 = b1[n], b1v1 = b1[16 + n];
    const float b2v = b2[n], w3v = W3[n], b3v = b3[0];
    const float invT = 1.0f / temp[0];

    short* hl = &h1lds[w][0];
    const long long eb = (long long)blockIdx.x * 256 + (long long)w * 64;

    for (int it = 0; it < 4; ++it) {
        const long long base = eb + it * 16;
        if (base >= E) break;
        long long e  = base + n;
        long long ec = (e < E) ? e : (long long)(E - 1);
        const int rn = ei[ec];
        const int cn = ei[(size_t)E + ec];

        f32x4 acc0 = {0.f,0.f,0.f,0.f}, acc1 = {0.f,0.f,0.f,0.f};
#pragma unroll
        for (int q = 0; q < 4; ++q) {
            const int node = (q < 2) ? rn : cn;
            const int elem = ((q & 1) * 32) + g * 8;
            short8v a = conv8(x + ((long long)node * 64 + elem));
            acc0 = __builtin_amdgcn_mfma_f32_16x16x32_bf16(a, B1f[0][q], acc0, 0, 0, 0);
            acc1 = __builtin_amdgcn_mfma_f32_16x16x32_bf16(a, B1f[1][q], acc1, 0, 0, 0);
        }
#pragma unroll
        for (int j = 0; j < 4; ++j) {
            const int m = g * 4 + j;
            hl[m * 40 + n]      = (short)f32_bf16(fmaxf(acc0[j] + b1v0, 0.f));
            hl[m * 40 + 16 + n] = (short)f32_bf16(fmaxf(acc1[j] + b1v1, 0.f));
        }
        const short8v a2 = *(const short8v*)(hl + ((l & 15) * 40 + g * 8));
        f32x4 acc2 = {0.f,0.f,0.f,0.f};
        acc2 = __builtin_amdgcn_mfma_f32_16x16x32_bf16(a2, B2f, acc2, 0, 0, 0);

        float p0 = w3v * fmaxf(acc2[0] + b2v, 0.f);
        float p1 = w3v * fmaxf(acc2[1] + b2v, 0.f);
        float p2 = w3v * fmaxf(acc2[2] + b2v, 0.f);
        float p3 = w3v * fmaxf(acc2[3] + b2v, 0.f);
#pragma unroll
        for (int mask = 1; mask <= 8; mask <<= 1) {
            p0 += __shfl_xor(p0, mask, 16);
            p1 += __shfl_xor(p1, mask, 16);
            p2 += __shfl_xor(p2, mask, 16);
            p3 += __shfl_xor(p3, mask, 16);
        }
        if (n < 4) {
            const float pv = (n == 0) ? p0 : ((n == 1) ? p1 : ((n == 2) ? p2 : p3));
            const float ew = 1.0f / (1.0f + __expf(-(pv + b3v)));
            const float o  = 1.0f / (1.0f + __expf(-ew * invT));
            const long long eo = base + g * 4 + n;
            if (eo < E) out[eo] = o;
        }
    }
}

extern "C" void kernel_launch(void* const* d_in, const int* in_sizes, int n_in,
                              void* d_out, int out_size, void* d_ws, size_t ws_size,
                              hipStream_t stream)
{
    const float* x    = (const float*)d_in[0];
    const int*   ei   = (const int*)  d_in[1];
    const float* W1   = (const float*)d_in[2];
    const float* b1   = (const float*)d_in[3];
    const float* W2   = (const float*)d_in[4];
    const float* b2   = (const float*)d_in[5];
    const float* W3   = (const float*)d_in[6];
    const float* b3   = (const float*)d_in[7];
    const float* temp = (const float*)d_in[8];
    float* out = (float*)d_out;

    const int E = in_sizes[1] / 2;            // edge_index is [2, E]
    const int N = in_sizes[0] / 64;           // nodes
    const size_t tabBytes = (size_t)N * 64;   // ya + yb, int8 [N][32] each

    const int eblocks = (E + 255) / 256;
    const int pblocks = (N + 63) / 64;

    if (ws_size >= tabBytes) {
        char* yat = (char*)d_ws;
        char* ybt = yat + (size_t)N * 32;
        precompute_y<<<pblocks, 256, 0, stream>>>(x, W1, b1, yat, ybt, N);
        if (E % 256 == 0) {
            edge_mlp_v9<true><<<eblocks, 256, 0, stream>>>(
                yat, ybt, ei, W2, b2, W3, b3, temp, out, E);
        } else {
            edge_mlp_v9<false><<<eblocks, 256, 0, stream>>>(
                yat, ybt, ei, W2, b2, W3, b3, temp, out, E);
        }
    } else {
        edge_mlp_direct<<<eblocks, 256, 0, stream>>>(
            x, ei, W1, b1, W2, b2, W3, b3, temp, out, E);
    }
}